// Round 17
// baseline (188.670 us; speedup 1.0000x reference)
//
#include <hip/hip_runtime.h>

#define N_NODES 4096
#define N_EDGES 131072
#define DIM     256
#define HEADS   8
#define HDIM    32
#define MAXDEG  320
#define MAXDEGP 321   // (321h+t)%32 = (h+t)%32 -> 8 heads hit distinct banks
#define WS_EFB_BYTES 94163200ull

typedef unsigned short u16;
typedef unsigned int   u32;

using f32x4  = __attribute__((ext_vector_type(4))) float;
using bf16x8 = __attribute__((ext_vector_type(8))) short;
using u16x4  = __attribute__((ext_vector_type(4))) unsigned short;
using u16x8  = __attribute__((ext_vector_type(8))) unsigned short;

__device__ __forceinline__ u16 f2bf(float f) {
  u32 u = __float_as_uint(f);
  u += 0x7fffu + ((u >> 16) & 1u);   // RNE
  return (u16)(u >> 16);
}
__device__ __forceinline__ float bf2f(u16 u) {
  return __uint_as_float(((u32)u) << 16);
}
__device__ __forceinline__ float dot4(float4 a, float4 b) {
  return a.x * b.x + a.y * b.y + a.z * b.z + a.w * b.w;
}

// ---------------------------------------------------------------------------
// Weight prep (+ deg zeroing folded in: blocks 1536..1551)
// ---------------------------------------------------------------------------
__global__ __launch_bounds__(256) void prep_w_k(
    const float* __restrict__ Wq, const float* __restrict__ Wk,
    const float* __restrict__ Wv, const float* __restrict__ Wi,
    const float* __restrict__ We, const float* __restrict__ Wo,
    const float* __restrict__ bq, const float* __restrict__ bk,
    const float* __restrict__ bv, const float* __restrict__ bi,
    u16* __restrict__ WcatT, u16* __restrict__ WeT, u16* __restrict__ WoT,
    float* __restrict__ bcat, int* __restrict__ deg)
{
  int n = blockIdx.x;
  int k = threadIdx.x;
  if (n < 1024) {
    const float* W = (n < 256) ? Wq : (n < 512) ? Wk : (n < 768) ? Wv : Wi;
    int nn = n & 255;
    WcatT[(size_t)n * 256 + k] = f2bf(W[(size_t)k * 256 + nn]);
    if (k == 0) {
      const float* b = (n < 256) ? bq : (n < 512) ? bk : (n < 768) ? bv : bi;
      bcat[n] = b[nn];
    }
  } else if (n < 1280) {
    int nn = n - 1024;
    WeT[(size_t)nn * 256 + k] = f2bf(We[(size_t)k * 256 + nn]);
  } else if (n < 1536) {
    int nn = n - 1280;
    WoT[(size_t)nn * 256 + k] = f2bf(Wo[(size_t)k * 256 + nn]);
  } else {
    deg[(n - 1536) * 256 + k] = 0;
  }
}

// ---------------------------------------------------------------------------
// 128x256 GEMM body, 512 threads / 8 waves. MODE 0: edge GEMM -> outE fp32
// (+ EfCSR bf16 scatter-write at epos if EFB). MODE 1: QKVI GEMM (+ compact
// bf16 Kb/Vb when the column tile covers K / V). MODE 2: Wo GEMM with fused
// LayerNorm(x_proj + preo) -> outN (no intermediate buffer).
// nt A-loads (A read exactly once); LDS dbuf; lgkmcnt-only barrier; swizzle.
// ---------------------------------------------------------------------------
template<int MODE, bool EFB>
__device__ __forceinline__ void gemm_big_body(
    const float* __restrict__ A, const u16* __restrict__ BT,
    const float* __restrict__ bias, float* __restrict__ C, int Nn,
    int m0, int nc0,
    const int* __restrict__ epos, u16* __restrict__ EfCSR,
    u16* __restrict__ Kb, u16* __restrict__ Vb,
    const float* __restrict__ QKVI, const float* __restrict__ lng,
    const float* __restrict__ lnb, float* __restrict__ outN,
    u16 (&As)[2][128 * 32], u16 (&Bs)[2][256 * 32])
{
  const int tid = threadIdx.x;          // 0..511
  const int w = tid >> 6, l = tid & 63;
  const int wr = w >> 2, wc = w & 3;
  const int fr = l & 15, hi = l >> 4;

  f32x4 pa[2];
  u16x8 pb[2];
  f32x4 acc[4][4] = {};

  auto loadstep = [&](int kt) {
#pragma unroll
    for (int i = 0; i < 2; ++i) {
      int j = tid + 512 * i;
      pa[i] = __builtin_nontemporal_load(
          (const f32x4*)(A + (size_t)(m0 + (j >> 3)) * 256 + kt * 32 + ((j & 7) << 2)));
    }
#pragma unroll
    for (int i = 0; i < 2; ++i) {
      int j = tid + 512 * i;
      pb[i] = *(const u16x8*)(BT + (size_t)(nc0 + (j >> 2)) * 256 + kt * 32 + ((j & 3) << 3));
    }
  };
  auto storestep = [&](int buf) {
#pragma unroll
    for (int i = 0; i < 2; ++i) {
      int j = tid + 512 * i;
      int row = j >> 3;
      int c16 = (j & 7) >> 1, half = j & 1;
      int swc = (c16 + ((row >> 1) & 3)) & 3;
      u16x4 u;
      u.x = f2bf(pa[i][0]); u.y = f2bf(pa[i][1]); u.z = f2bf(pa[i][2]); u.w = f2bf(pa[i][3]);
      *(u16x4*)&As[buf][row * 32 + swc * 8 + half * 4] = u;
    }
#pragma unroll
    for (int i = 0; i < 2; ++i) {
      int j = tid + 512 * i;
      int row = j >> 2;
      int swc = ((j & 3) + ((row >> 1) & 3)) & 3;
      *(u16x8*)&Bs[buf][row * 32 + swc * 8] = pb[i];
    }
  };

  loadstep(0);
  storestep(0);

#pragma unroll
  for (int kt = 0; kt < 8; ++kt) {
    if (kt < 7) loadstep(kt + 1);
    __builtin_amdgcn_sched_barrier(0);
    asm volatile("s_waitcnt lgkmcnt(0)" ::: "memory");
    __builtin_amdgcn_s_barrier();
    __builtin_amdgcn_sched_barrier(0);
    const int cur = kt & 1;
    bf16x8 a[4], b[4];
#pragma unroll
    for (int mi = 0; mi < 4; ++mi) {
      int rA = wr * 64 + mi * 16 + fr;
      int swc = (hi + ((rA >> 1) & 3)) & 3;
      a[mi] = *(const bf16x8*)&As[cur][rA * 32 + swc * 8];
    }
#pragma unroll
    for (int ni = 0; ni < 4; ++ni) {
      int rB = wc * 64 + ni * 16 + fr;
      int swc = (hi + ((rB >> 1) & 3)) & 3;
      b[ni] = *(const bf16x8*)&Bs[cur][rB * 32 + swc * 8];
    }
#pragma unroll
    for (int mi = 0; mi < 4; ++mi)
#pragma unroll
      for (int ni = 0; ni < 4; ++ni)
        acc[mi][ni] = __builtin_amdgcn_mfma_f32_16x16x32_bf16(
            b[ni], a[mi], acc[mi][ni], 0, 0, 0);
    if (kt < 7) storestep((kt + 1) & 1);
  }

  if constexpr (MODE == 0) {
    // edge GEMM: outE fp32 (+ bf16 CSR-ordered copy for node_attn)
#pragma unroll
    for (int mi = 0; mi < 4; ++mi) {
      int row = m0 + wr * 64 + mi * 16 + fr;     // edge id
      int p = 0;
      if (EFB) p = epos[row];
#pragma unroll
      for (int ni = 0; ni < 4; ++ni) {
        int col = wc * 64 + ni * 16 + hi * 4;
        float4 bv = *(const float4*)&bias[col];
        f32x4 v = acc[mi][ni];
        float4 o;
        o.x = v[0] + bv.x; o.y = v[1] + bv.y; o.z = v[2] + bv.z; o.w = v[3] + bv.w;
        *(float4*)&C[(size_t)row * 256 + col] = o;
        if (EFB) {
          u16x4 ub;
          ub.x = f2bf(o.x); ub.y = f2bf(o.y); ub.z = f2bf(o.z); ub.w = f2bf(o.w);
          *(u16x4*)&EfCSR[(size_t)p * 256 + col] = ub;
        }
      }
    }
  } else if constexpr (MODE == 1) {
    // QKVI GEMM (+ compact bf16 K/V tables)
#pragma unroll
    for (int mi = 0; mi < 4; ++mi) {
      int row = m0 + wr * 64 + mi * 16 + fr;
#pragma unroll
      for (int ni = 0; ni < 4; ++ni) {
        int col = nc0 + wc * 64 + ni * 16 + hi * 4;
        float4 bv = *(const float4*)&bias[col];
        f32x4 v = acc[mi][ni];
        float4 o;
        o.x = v[0] + bv.x; o.y = v[1] + bv.y; o.z = v[2] + bv.z; o.w = v[3] + bv.w;
        *(float4*)&C[(size_t)row * 1024 + col] = o;
        u16x4 ub;
        ub.x = f2bf(o.x); ub.y = f2bf(o.y); ub.z = f2bf(o.z); ub.w = f2bf(o.w);
        if (nc0 == 256) *(u16x4*)&Kb[(size_t)row * 256 + (col - 256)] = ub;
        if (nc0 == 512) *(u16x4*)&Vb[(size_t)row * 256 + (col - 512)] = ub;
      }
    }
  } else {
    // Wo GEMM + fused LayerNorm(x_proj + preo) -> outN
    __syncthreads();                      // all As/Bs reads done; reuse as scratch
    float* s_sum = (float*)&As[0][0];     // [128][16]
    float* s_sq  = (float*)&As[1][0];     // [128][16]
#pragma unroll
    for (int mi = 0; mi < 4; ++mi) {
      int r = wr * 64 + mi * 16 + fr;
      int row = m0 + r;
      float ps = 0.f, pq = 0.f;
#pragma unroll
      for (int ni = 0; ni < 4; ++ni) {
        int col = wc * 64 + ni * 16 + hi * 4;
        float4 bv = *(const float4*)&bias[col];
        float4 xp = *(const float4*)&QKVI[(size_t)row * 1024 + 768 + col];
        acc[mi][ni][0] += bv.x + xp.x;
        acc[mi][ni][1] += bv.y + xp.y;
        acc[mi][ni][2] += bv.z + xp.z;
        acc[mi][ni][3] += bv.w + xp.w;
#pragma unroll
        for (int j = 0; j < 4; ++j) {
          float vv = acc[mi][ni][j];
          ps += vv; pq += vv * vv;
        }
      }
      s_sum[r * 16 + wc * 4 + hi] = ps;
      s_sq [r * 16 + wc * 4 + hi] = pq;
    }
    __syncthreads();
    float* s_mu = (float*)&Bs[0][0];
    float* s_rs = s_mu + 128;
    if (tid < 128) {
      float s = 0.f, q = 0.f;
#pragma unroll
      for (int k = 0; k < 16; ++k) { s += s_sum[tid * 16 + k]; q += s_sq[tid * 16 + k]; }
      float mu = s * (1.0f / 256.0f);
      float var = q * (1.0f / 256.0f) - mu * mu;
      s_mu[tid] = mu;
      s_rs[tid] = rsqrtf(var + 1e-5f);
    }
    __syncthreads();
#pragma unroll
    for (int mi = 0; mi < 4; ++mi) {
      int r = wr * 64 + mi * 16 + fr;
      int row = m0 + r;
      float mu = s_mu[r], rs = s_rs[r];
#pragma unroll
      for (int ni = 0; ni < 4; ++ni) {
        int col = wc * 64 + ni * 16 + hi * 4;
        float4 g4 = *(const float4*)&lng[col];
        float4 b4 = *(const float4*)&lnb[col];
        float4 o;
        o.x = (acc[mi][ni][0] - mu) * rs * g4.x + b4.x;
        o.y = (acc[mi][ni][1] - mu) * rs * g4.y + b4.y;
        o.z = (acc[mi][ni][2] - mu) * rs * g4.z + b4.z;
        o.w = (acc[mi][ni][3] - mu) * rs * g4.w + b4.w;
        *(float4*)&outN[(size_t)row * 256 + col] = o;
      }
    }
  }
}

// Merged dispatch: 1152 blocks = 1024 edge (128x256) + 128 QKVI, every 9th = QKVI.
template<bool EFB>
__global__ __launch_bounds__(512) void gemm_all_k(
    const float* __restrict__ ea, const u16* __restrict__ WeT,
    const float* __restrict__ be, float* __restrict__ outE,
    const float* __restrict__ x, const u16* __restrict__ WcatT,
    const float* __restrict__ bcat, float* __restrict__ QKVI,
    const int* __restrict__ epos, u16* __restrict__ EfCSR,
    u16* __restrict__ Kb, u16* __restrict__ Vb)
{
  __shared__ u16 As[2][128 * 32];
  __shared__ u16 Bs[2][256 * 32];
  int bid = blockIdx.x;
  int r = bid % 9, q = bid / 9;
  if (r < 8) {
    int j = q * 8 + r;                        // 0..1023
    gemm_big_body<0, EFB>(ea, WeT, be, outE, 256, j * 128, 0,
                          epos, EfCSR, Kb, Vb, nullptr, nullptr, nullptr, nullptr, As, Bs);
  } else {
    gemm_big_body<1, EFB>(x, WcatT, bcat, QKVI, 1024, (q >> 2) * 128, (q & 3) * 256,
                          nullptr, nullptr, Kb, Vb, nullptr, nullptr, nullptr, nullptr, As, Bs);
  }
}

// Wo projection + fused LayerNorm: outN = LN(x_proj + agg @ Wo + bo)
__global__ __launch_bounds__(512) void gemm_wo_k(
    const float* __restrict__ agg, const u16* __restrict__ WoT,
    const float* __restrict__ bo, const float* __restrict__ QKVI,
    const float* __restrict__ lng, const float* __restrict__ lnb,
    float* __restrict__ outN)
{
  __shared__ u16 As[2][128 * 32];
  __shared__ u16 Bs[2][256 * 32];
  gemm_big_body<2, false>(agg, WoT, bo, nullptr, 256, blockIdx.x * 128, 0,
                          nullptr, nullptr, nullptr, nullptr, QKVI, lng, lnb, outN, As, Bs);
}

// ---------------------------------------------------------------------------
// CSR build
// ---------------------------------------------------------------------------
__global__ __launch_bounds__(256) void hist_k(const int* __restrict__ src, int* __restrict__ deg)
{
  int e = blockIdx.x * 256 + threadIdx.x;
  if (e < N_EDGES) atomicAdd(&deg[src[e]], 1);
}

__global__ __launch_bounds__(1024) void scan_k(const int* __restrict__ deg,
                                               int* __restrict__ rowstart,
                                               int* __restrict__ cursor)
{
  __shared__ int s[1024];
  int tid = threadIdx.x;
  int4 v = ((const int4*)deg)[tid];
  int sum = v.x + v.y + v.z + v.w;
  s[tid] = sum;
  __syncthreads();
  for (int off = 1; off < 1024; off <<= 1) {
    int t = (tid >= off) ? s[tid - off] : 0;
    __syncthreads();
    s[tid] += t;
    __syncthreads();
  }
  int excl = s[tid] - sum;
  int r0 = excl, r1 = excl + v.x, r2 = r1 + v.y, r3 = r2 + v.z;
  rowstart[4 * tid + 0] = r0; cursor[4 * tid + 0] = r0;
  rowstart[4 * tid + 1] = r1; cursor[4 * tid + 1] = r1;
  rowstart[4 * tid + 2] = r2; cursor[4 * tid + 2] = r2;
  rowstart[4 * tid + 3] = r3; cursor[4 * tid + 3] = r3;
  if (tid == 1023) rowstart[4096] = r3 + v.w;
}

__global__ __launch_bounds__(256) void scatter_k(const int* __restrict__ src,
                                                 int* __restrict__ cursor,
                                                 int* __restrict__ csr,
                                                 int* __restrict__ epos)
{
  int e = blockIdx.x * 256 + threadIdx.x;
  if (e < N_EDGES) {
    int p = atomicAdd(&cursor[src[e]], 1);
    csr[p] = e;
    epos[e] = p;
  }
}

// ---------------------------------------------------------------------------
// Fused per-node kernel. EFB: logits stream EfCSR (bf16, CSR-ordered, written
// by the edge GEMM) sequentially; K/V gathers hit compact bf16 tables (2MB,
// L2-resident). Fallback (!EFB): fp32 Ef gathers as before.
// ---------------------------------------------------------------------------
template<bool EFB>
__global__ __launch_bounds__(256) void node_attn_k(
    const float* __restrict__ QKVI, const float* __restrict__ Ef,
    const u16* __restrict__ EfCSR, const u16* __restrict__ Kb,
    const u16* __restrict__ Vb,
    const int* __restrict__ rowstart, const int* __restrict__ csr,
    const int* __restrict__ tgt, float* __restrict__ agg)
{
  __shared__ int   s_eid[MAXDEG];
  __shared__ int   s_tgt[MAXDEG];
  __shared__ float s_sc[HEADS][MAXDEGP];
  __shared__ unsigned char s_alive[MAXDEG];
  __shared__ float s_self[8];
  __shared__ float s_wself[8];

  const float scl = 0.17677669529663687f;
  int i = blockIdx.x;
  int base = rowstart[i];
  int deg = rowstart[i + 1] - base;
  if (deg > MAXDEG) deg = MAXDEG;
  int tid = threadIdx.x;
  int w = tid >> 6, l = tid & 63;
  int h = tid >> 5, d = tid & 31;

  for (int t = tid; t < deg; t += 256) {
    int e = csr[base + t];
    s_eid[t] = e;
    s_tgt[t] = tgt[e];
  }
  __syncthreads();

  // Q_i: lane l holds dims 4l..4l+3
  float4 q4 = *(const float4*)&QKVI[(size_t)i * 1024 + 4 * l];

  // self score (wave 0): K from bf16 table
  if (w == 0) {
    u16x4 kb = *(const u16x4*)&Kb[(size_t)i * 256 + 4 * l];
    float4 k4 = make_float4(bf2f(kb.x), bf2f(kb.y), bf2f(kb.z), bf2f(kb.w));
    float c = dot4(q4, k4);
    c += __shfl_xor(c, 1); c += __shfl_xor(c, 2); c += __shfl_xor(c, 4);
    if ((l & 7) == 0) s_self[l >> 3] = c * scl;
  }

  // edge logits: 4 edges per wave iteration, batched loads
  for (int t0 = w; t0 < deg; t0 += 16) {
    float4 ef[4], k4[4];
#pragma unroll
    for (int u = 0; u < 4; ++u) {
      int t = t0 + 4 * u;
      if (t < deg) {
        if (EFB) {
          u16x4 ub = *(const u16x4*)&EfCSR[(size_t)(base + t) * 256 + 4 * l];
          ef[u] = make_float4(bf2f(ub.x), bf2f(ub.y), bf2f(ub.z), bf2f(ub.w));
        } else {
          ef[u] = *(const float4*)&Ef[(size_t)s_eid[t] * 256 + 4 * l];
        }
        u16x4 kb = *(const u16x4*)&Kb[(size_t)s_tgt[t] * 256 + 4 * l];
        k4[u] = make_float4(bf2f(kb.x), bf2f(kb.y), bf2f(kb.z), bf2f(kb.w));
      }
    }
#pragma unroll
    for (int u = 0; u < 4; ++u) {
      int t = t0 + 4 * u;
      if (t < deg) {
        float c = dot4(q4, ef[u]) + dot4(ef[u], k4[u]) + dot4(q4, k4[u]);
        c += __shfl_xor(c, 1); c += __shfl_xor(c, 2); c += __shfl_xor(c, 4);
        if ((l & 7) == 0) s_sc[l >> 3][t] = c * scl;
      }
    }
  }

  // dedup (keep max eid per tgt), drop self-target
  for (int t = tid; t < deg; t += 256) {
    int tt = s_tgt[t], ee = s_eid[t];
    bool alive = (tt != i);
    if (alive)
      for (int u = 0; u < deg; ++u)
        if (s_tgt[u] == tt && s_eid[u] > ee) { alive = false; break; }
    s_alive[t] = alive ? 1 : 0;
  }
  __syncthreads();

  // softmax: 32 lanes per head; dead edges get weight exactly 0
  {
    float m = s_self[h];
    for (int t = d; t < deg; t += 32)
      if (s_alive[t]) m = fmaxf(m, s_sc[h][t]);
#pragma unroll
    for (int off = 16; off > 0; off >>= 1) m = fmaxf(m, __shfl_xor(m, off, 32));
    float lsum = 0.f;
    for (int t = d; t < deg; t += 32) {
      float wv = s_alive[t] ? expf(s_sc[h][t] - m) : 0.f;
      s_sc[h][t] = wv;
      lsum += wv;
    }
#pragma unroll
    for (int off = 16; off > 0; off >>= 1) lsum += __shfl_xor(lsum, off, 32);
    float wself = expf(s_self[h] - m);
    float inv = 1.f / (lsum + wself);
    if (d == 0) s_wself[h] = wself * inv;
    for (int t = d; t < deg; t += 32) s_sc[h][t] *= inv;
  }
  __syncthreads();

  // aggregate V from bf16 table (L2-resident); col = tid -> coalesced
  int col = tid;
  float accv = s_wself[h] * bf2f(Vb[(size_t)i * 256 + col]);
  int t0 = 0;
  for (; t0 + 4 <= deg; t0 += 4) {
    float vl[4];
#pragma unroll
    for (int u = 0; u < 4; ++u)
      vl[u] = bf2f(Vb[(size_t)s_tgt[t0 + u] * 256 + col]);
#pragma unroll
    for (int u = 0; u < 4; ++u)
      accv += s_sc[h][t0 + u] * vl[u];
  }
  for (; t0 < deg; ++t0)
    accv += s_sc[h][t0] * bf2f(Vb[(size_t)s_tgt[t0] * 256 + col]);
  agg[(size_t)i * 256 + col] = accv;
}

// ---------------------------------------------------------------------------
extern "C" void kernel_launch(void* const* d_in, const int* in_sizes, int n_in,
                              void* d_out, int out_size, void* d_ws, size_t ws_size,
                              hipStream_t stream) {
  (void)in_sizes; (void)n_in; (void)out_size;
  const float* x  = (const float*)d_in[0];
  const int*   ei = (const int*)d_in[1];
  const float* ea = (const float*)d_in[2];
  const float* Wq = (const float*)d_in[3];  const float* bq = (const float*)d_in[4];
  const float* Wk = (const float*)d_in[5];  const float* bk = (const float*)d_in[6];
  const float* Wv = (const float*)d_in[7];  const float* bv = (const float*)d_in[8];
  const float* We = (const float*)d_in[9];  const float* be = (const float*)d_in[10];
  const float* Wo = (const float*)d_in[11]; const float* bo = (const float*)d_in[12];
  const float* Wi = (const float*)d_in[13]; const float* bi = (const float*)d_in[14];
  const float* lng = (const float*)d_in[15]; const float* lnb = (const float*)d_in[16];

  const int* src = ei;
  const int* tgt = ei + N_EDGES;

  char* ws = (char*)d_ws;
  u16*   WcatT   = (u16*)(ws + 0);              //  512 KB
  u16*   WeT     = (u16*)(ws + 524288);         //  128 KB
  u16*   WoT     = (u16*)(ws + 655360);         //  128 KB
  float* bcat    = (float*)(ws + 786432);       //    4 KB
  float* QKVI    = (float*)(ws + 790528);       //   16 MB
  int*   deg     = (int*)(ws + 17567744);       //   16 KB
  int*   rowstart= (int*)(ws + 17584128);       //   16.25 KB
  int*   cursor  = (int*)(ws + 17600768);       //   16 KB
  int*   csr     = (int*)(ws + 17617152);       //  512 KB
  int*   epos    = (int*)(ws + 18141440);       //  512 KB
  float* agg     = (float*)(ws + 18665728);     //    4 MB
  u16*   Kb      = (u16*)(ws + 22860032);       //    2 MB
  u16*   Vb      = (u16*)(ws + 24957184);       //    2 MB
  u16*   EfCSR   = (u16*)(ws + 27054336);       //   64 MB (optional)

  float* outN = (float*)d_out;
  float* outE = (float*)d_out + (size_t)N_NODES * DIM;

  const bool efb = ws_size >= WS_EFB_BYTES;

  prep_w_k<<<1552, 256, 0, stream>>>(Wq, Wk, Wv, Wi, We, Wo, bq, bk, bv, bi,
                                     WcatT, WeT, WoT, bcat, deg);

  hist_k<<<N_EDGES / 256, 256, 0, stream>>>(src, deg);
  scan_k<<<1, 1024, 0, stream>>>(deg, rowstart, cursor);
  scatter_k<<<N_EDGES / 256, 256, 0, stream>>>(src, cursor, csr, epos);

  if (efb)
    gemm_all_k<true><<<1152, 512, 0, stream>>>(ea, WeT, be, outE, x, WcatT, bcat,
                                               QKVI, epos, EfCSR, Kb, Vb);
  else
    gemm_all_k<false><<<1152, 512, 0, stream>>>(ea, WeT, be, outE, x, WcatT, bcat,
                                                QKVI, epos, EfCSR, Kb, Vb);

  if (efb)
    node_attn_k<true><<<N_NODES, 256, 0, stream>>>(QKVI, outE, EfCSR, Kb, Vb,
                                                   rowstart, csr, tgt, agg);
  else
    node_attn_k<false><<<N_NODES, 256, 0, stream>>>(QKVI, outE, EfCSR, Kb, Vb,
                                                    rowstart, csr, tgt, agg);

  // preo GEMM + fused LayerNorm -> outN
  gemm_wo_k<<<N_NODES / 128, 512, 0, stream>>>(agg, WoT, bo, QKVI, lng, lnb, outN);
}

// Round 18
// 173.334 us; speedup vs baseline: 1.0885x; 1.0885x over previous
//
#include <hip/hip_runtime.h>

#define N_NODES 4096
#define N_EDGES 131072
#define DIM     256
#define HEADS   8
#define HDIM    32
#define MAXDEG  320
#define MAXDEGP 321   // (321h+t)%32 = (h+t)%32 -> 8 heads hit distinct banks

typedef unsigned short u16;
typedef unsigned int   u32;

using f32x4  = __attribute__((ext_vector_type(4))) float;
using bf16x8 = __attribute__((ext_vector_type(8))) short;
using u16x4  = __attribute__((ext_vector_type(4))) unsigned short;
using u16x8  = __attribute__((ext_vector_type(8))) unsigned short;

__device__ __forceinline__ u16 f2bf(float f) {
  u32 u = __float_as_uint(f);
  u += 0x7fffu + ((u >> 16) & 1u);   // RNE
  return (u16)(u >> 16);
}
__device__ __forceinline__ float bf2f(u16 u) {
  return __uint_as_float(((u32)u) << 16);
}
__device__ __forceinline__ float dot4(float4 a, float4 b) {
  return a.x * b.x + a.y * b.y + a.z * b.z + a.w * b.w;
}

// ---------------------------------------------------------------------------
// Weight prep (+ deg zeroing folded in: blocks 1536..1551)
// ---------------------------------------------------------------------------
__global__ __launch_bounds__(256) void prep_w_k(
    const float* __restrict__ Wq, const float* __restrict__ Wk,
    const float* __restrict__ Wv, const float* __restrict__ Wi,
    const float* __restrict__ We, const float* __restrict__ Wo,
    const float* __restrict__ bq, const float* __restrict__ bk,
    const float* __restrict__ bv, const float* __restrict__ bi,
    u16* __restrict__ WcatT, u16* __restrict__ WeT, u16* __restrict__ WoT,
    float* __restrict__ bcat, int* __restrict__ deg)
{
  int n = blockIdx.x;
  int k = threadIdx.x;
  if (n < 1024) {
    const float* W = (n < 256) ? Wq : (n < 512) ? Wk : (n < 768) ? Wv : Wi;
    int nn = n & 255;
    WcatT[(size_t)n * 256 + k] = f2bf(W[(size_t)k * 256 + nn]);
    if (k == 0) {
      const float* b = (n < 256) ? bq : (n < 512) ? bk : (n < 768) ? bv : bi;
      bcat[n] = b[nn];
    }
  } else if (n < 1280) {
    int nn = n - 1024;
    WeT[(size_t)nn * 256 + k] = f2bf(We[(size_t)k * 256 + nn]);
  } else if (n < 1536) {
    int nn = n - 1280;
    WoT[(size_t)nn * 256 + k] = f2bf(Wo[(size_t)k * 256 + nn]);
  } else {
    deg[(n - 1536) * 256 + k] = 0;
  }
}

// ---------------------------------------------------------------------------
// 128x256 GEMM body, 512 threads / 8 waves. MODE 0: edge GEMM -> outE fp32.
// MODE 1: QKVI GEMM (+ compact bf16 Kb/Vb when the column tile covers K/V).
// MODE 2: Wo GEMM with fused LayerNorm(x_proj + preo) -> outN.
// nt A-loads (A read exactly once); LDS dbuf; lgkmcnt-only barrier; swizzle.
// ---------------------------------------------------------------------------
template<int MODE>
__device__ __forceinline__ void gemm_big_body(
    const float* __restrict__ A, const u16* __restrict__ BT,
    const float* __restrict__ bias, float* __restrict__ C, int Nn,
    int m0, int nc0,
    u16* __restrict__ Kb, u16* __restrict__ Vb,
    const float* __restrict__ QKVI, const float* __restrict__ lng,
    const float* __restrict__ lnb, float* __restrict__ outN,
    u16 (&As)[2][128 * 32], u16 (&Bs)[2][256 * 32])
{
  const int tid = threadIdx.x;          // 0..511
  const int w = tid >> 6, l = tid & 63;
  const int wr = w >> 2, wc = w & 3;
  const int fr = l & 15, hi = l >> 4;

  f32x4 pa[2];
  u16x8 pb[2];
  f32x4 acc[4][4] = {};

  auto loadstep = [&](int kt) {
#pragma unroll
    for (int i = 0; i < 2; ++i) {
      int j = tid + 512 * i;
      pa[i] = __builtin_nontemporal_load(
          (const f32x4*)(A + (size_t)(m0 + (j >> 3)) * 256 + kt * 32 + ((j & 7) << 2)));
    }
#pragma unroll
    for (int i = 0; i < 2; ++i) {
      int j = tid + 512 * i;
      pb[i] = *(const u16x8*)(BT + (size_t)(nc0 + (j >> 2)) * 256 + kt * 32 + ((j & 3) << 3));
    }
  };
  auto storestep = [&](int buf) {
#pragma unroll
    for (int i = 0; i < 2; ++i) {
      int j = tid + 512 * i;
      int row = j >> 3;
      int c16 = (j & 7) >> 1, half = j & 1;
      int swc = (c16 + ((row >> 1) & 3)) & 3;
      u16x4 u;
      u.x = f2bf(pa[i][0]); u.y = f2bf(pa[i][1]); u.z = f2bf(pa[i][2]); u.w = f2bf(pa[i][3]);
      *(u16x4*)&As[buf][row * 32 + swc * 8 + half * 4] = u;
    }
#pragma unroll
    for (int i = 0; i < 2; ++i) {
      int j = tid + 512 * i;
      int row = j >> 2;
      int swc = ((j & 3) + ((row >> 1) & 3)) & 3;
      *(u16x8*)&Bs[buf][row * 32 + swc * 8] = pb[i];
    }
  };

  loadstep(0);
  storestep(0);

#pragma unroll
  for (int kt = 0; kt < 8; ++kt) {
    if (kt < 7) loadstep(kt + 1);
    __builtin_amdgcn_sched_barrier(0);
    asm volatile("s_waitcnt lgkmcnt(0)" ::: "memory");
    __builtin_amdgcn_s_barrier();
    __builtin_amdgcn_sched_barrier(0);
    const int cur = kt & 1;
    bf16x8 a[4], b[4];
#pragma unroll
    for (int mi = 0; mi < 4; ++mi) {
      int rA = wr * 64 + mi * 16 + fr;
      int swc = (hi + ((rA >> 1) & 3)) & 3;
      a[mi] = *(const bf16x8*)&As[cur][rA * 32 + swc * 8];
    }
#pragma unroll
    for (int ni = 0; ni < 4; ++ni) {
      int rB = wc * 64 + ni * 16 + fr;
      int swc = (hi + ((rB >> 1) & 3)) & 3;
      b[ni] = *(const bf16x8*)&Bs[cur][rB * 32 + swc * 8];
    }
#pragma unroll
    for (int mi = 0; mi < 4; ++mi)
#pragma unroll
      for (int ni = 0; ni < 4; ++ni)
        acc[mi][ni] = __builtin_amdgcn_mfma_f32_16x16x32_bf16(
            b[ni], a[mi], acc[mi][ni], 0, 0, 0);
    if (kt < 7) storestep((kt + 1) & 1);
  }

  if constexpr (MODE == 0) {
    // edge GEMM: outE fp32
#pragma unroll
    for (int mi = 0; mi < 4; ++mi) {
      int row = m0 + wr * 64 + mi * 16 + fr;
#pragma unroll
      for (int ni = 0; ni < 4; ++ni) {
        int col = wc * 64 + ni * 16 + hi * 4;
        float4 bv = *(const float4*)&bias[col];
        f32x4 v = acc[mi][ni];
        float4 o;
        o.x = v[0] + bv.x; o.y = v[1] + bv.y; o.z = v[2] + bv.z; o.w = v[3] + bv.w;
        *(float4*)&C[(size_t)row * 256 + col] = o;
      }
    }
  } else if constexpr (MODE == 1) {
    // QKVI GEMM (+ compact bf16 K/V tables)
#pragma unroll
    for (int mi = 0; mi < 4; ++mi) {
      int row = m0 + wr * 64 + mi * 16 + fr;
#pragma unroll
      for (int ni = 0; ni < 4; ++ni) {
        int col = nc0 + wc * 64 + ni * 16 + hi * 4;
        float4 bv = *(const float4*)&bias[col];
        f32x4 v = acc[mi][ni];
        float4 o;
        o.x = v[0] + bv.x; o.y = v[1] + bv.y; o.z = v[2] + bv.z; o.w = v[3] + bv.w;
        *(float4*)&C[(size_t)row * 1024 + col] = o;
        u16x4 ub;
        ub.x = f2bf(o.x); ub.y = f2bf(o.y); ub.z = f2bf(o.z); ub.w = f2bf(o.w);
        if (nc0 == 256) *(u16x4*)&Kb[(size_t)row * 256 + (col - 256)] = ub;
        if (nc0 == 512) *(u16x4*)&Vb[(size_t)row * 256 + (col - 512)] = ub;
      }
    }
  } else {
    // Wo GEMM + fused LayerNorm(x_proj + preo) -> outN
    __syncthreads();                      // all As/Bs reads done; reuse as scratch
    float* s_sum = (float*)&As[0][0];     // [128][16]
    float* s_sq  = (float*)&As[1][0];     // [128][16]
#pragma unroll
    for (int mi = 0; mi < 4; ++mi) {
      int r = wr * 64 + mi * 16 + fr;
      int row = m0 + r;
      float ps = 0.f, pq = 0.f;
#pragma unroll
      for (int ni = 0; ni < 4; ++ni) {
        int col = wc * 64 + ni * 16 + hi * 4;
        float4 bv = *(const float4*)&bias[col];
        float4 xp = *(const float4*)&QKVI[(size_t)row * 1024 + 768 + col];
        acc[mi][ni][0] += bv.x + xp.x;
        acc[mi][ni][1] += bv.y + xp.y;
        acc[mi][ni][2] += bv.z + xp.z;
        acc[mi][ni][3] += bv.w + xp.w;
#pragma unroll
        for (int j = 0; j < 4; ++j) {
          float vv = acc[mi][ni][j];
          ps += vv; pq += vv * vv;
        }
      }
      s_sum[r * 16 + wc * 4 + hi] = ps;
      s_sq [r * 16 + wc * 4 + hi] = pq;
    }
    __syncthreads();
    float* s_mu = (float*)&Bs[0][0];
    float* s_rs = s_mu + 128;
    if (tid < 128) {
      float s = 0.f, q = 0.f;
#pragma unroll
      for (int k = 0; k < 16; ++k) { s += s_sum[tid * 16 + k]; q += s_sq[tid * 16 + k]; }
      float mu = s * (1.0f / 256.0f);
      float var = q * (1.0f / 256.0f) - mu * mu;
      s_mu[tid] = mu;
      s_rs[tid] = rsqrtf(var + 1e-5f);
    }
    __syncthreads();
#pragma unroll
    for (int mi = 0; mi < 4; ++mi) {
      int r = wr * 64 + mi * 16 + fr;
      int row = m0 + r;
      float mu = s_mu[r], rs = s_rs[r];
#pragma unroll
      for (int ni = 0; ni < 4; ++ni) {
        int col = wc * 64 + ni * 16 + hi * 4;
        float4 g4 = *(const float4*)&lng[col];
        float4 b4 = *(const float4*)&lnb[col];
        float4 o;
        o.x = (acc[mi][ni][0] - mu) * rs * g4.x + b4.x;
        o.y = (acc[mi][ni][1] - mu) * rs * g4.y + b4.y;
        o.z = (acc[mi][ni][2] - mu) * rs * g4.z + b4.z;
        o.w = (acc[mi][ni][3] - mu) * rs * g4.w + b4.w;
        *(float4*)&outN[(size_t)row * 256 + col] = o;
      }
    }
  }
}

// Merged dispatch: 1152 blocks = 1024 edge (128x256) + 128 QKVI, every 9th = QKVI.
__global__ __launch_bounds__(512) void gemm_all_k(
    const float* __restrict__ ea, const u16* __restrict__ WeT,
    const float* __restrict__ be, float* __restrict__ outE,
    const float* __restrict__ x, const u16* __restrict__ WcatT,
    const float* __restrict__ bcat, float* __restrict__ QKVI,
    u16* __restrict__ Kb, u16* __restrict__ Vb)
{
  __shared__ u16 As[2][128 * 32];
  __shared__ u16 Bs[2][256 * 32];
  int bid = blockIdx.x;
  int r = bid % 9, q = bid / 9;
  if (r < 8) {
    int j = q * 8 + r;                        // 0..1023
    gemm_big_body<0>(ea, WeT, be, outE, 256, j * 128, 0,
                     nullptr, nullptr, nullptr, nullptr, nullptr, nullptr, As, Bs);
  } else {
    gemm_big_body<1>(x, WcatT, bcat, QKVI, 1024, (q >> 2) * 128, (q & 3) * 256,
                     Kb, Vb, nullptr, nullptr, nullptr, nullptr, As, Bs);
  }
}

// Wo projection + fused LayerNorm: outN = LN(x_proj + agg @ Wo + bo)
__global__ __launch_bounds__(512) void gemm_wo_k(
    const float* __restrict__ agg, const u16* __restrict__ WoT,
    const float* __restrict__ bo, const float* __restrict__ QKVI,
    const float* __restrict__ lng, const float* __restrict__ lnb,
    float* __restrict__ outN)
{
  __shared__ u16 As[2][128 * 32];
  __shared__ u16 Bs[2][256 * 32];
  gemm_big_body<2>(agg, WoT, bo, nullptr, 256, blockIdx.x * 128, 0,
                   nullptr, nullptr, QKVI, lng, lnb, outN, As, Bs);
}

// ---------------------------------------------------------------------------
// CSR build
// ---------------------------------------------------------------------------
__global__ __launch_bounds__(256) void hist_k(const int* __restrict__ src, int* __restrict__ deg)
{
  int e = blockIdx.x * 256 + threadIdx.x;
  if (e < N_EDGES) atomicAdd(&deg[src[e]], 1);
}

__global__ __launch_bounds__(1024) void scan_k(const int* __restrict__ deg,
                                               int* __restrict__ rowstart,
                                               int* __restrict__ cursor)
{
  __shared__ int s[1024];
  int tid = threadIdx.x;
  int4 v = ((const int4*)deg)[tid];
  int sum = v.x + v.y + v.z + v.w;
  s[tid] = sum;
  __syncthreads();
  for (int off = 1; off < 1024; off <<= 1) {
    int t = (tid >= off) ? s[tid - off] : 0;
    __syncthreads();
    s[tid] += t;
    __syncthreads();
  }
  int excl = s[tid] - sum;
  int r0 = excl, r1 = excl + v.x, r2 = r1 + v.y, r3 = r2 + v.z;
  rowstart[4 * tid + 0] = r0; cursor[4 * tid + 0] = r0;
  rowstart[4 * tid + 1] = r1; cursor[4 * tid + 1] = r1;
  rowstart[4 * tid + 2] = r2; cursor[4 * tid + 2] = r2;
  rowstart[4 * tid + 3] = r3; cursor[4 * tid + 3] = r3;
  if (tid == 1023) rowstart[4096] = r3 + v.w;
}

__global__ __launch_bounds__(256) void scatter_k(const int* __restrict__ src,
                                                 int* __restrict__ cursor,
                                                 int* __restrict__ csr)
{
  int e = blockIdx.x * 256 + threadIdx.x;
  if (e < N_EDGES) {
    int p = atomicAdd(&cursor[src[e]], 1);
    csr[p] = e;
  }
}

// ---------------------------------------------------------------------------
// Fused per-node kernel (coalesced layout + 4-deep MLP). Ef gathers stay fp32
// (proven); K/V gathers hit compact bf16 tables (2MB each, L2-resident).
// ---------------------------------------------------------------------------
__global__ __launch_bounds__(256) void node_attn_k(
    const float* __restrict__ QKVI, const float* __restrict__ Ef,
    const u16* __restrict__ Kb, const u16* __restrict__ Vb,
    const int* __restrict__ rowstart, const int* __restrict__ csr,
    const int* __restrict__ tgt, float* __restrict__ agg)
{
  __shared__ int   s_eid[MAXDEG];
  __shared__ int   s_tgt[MAXDEG];
  __shared__ float s_sc[HEADS][MAXDEGP];
  __shared__ unsigned char s_alive[MAXDEG];
  __shared__ float s_self[8];
  __shared__ float s_wself[8];

  const float scl = 0.17677669529663687f;
  int i = blockIdx.x;
  int base = rowstart[i];
  int deg = rowstart[i + 1] - base;
  if (deg > MAXDEG) deg = MAXDEG;
  int tid = threadIdx.x;
  int w = tid >> 6, l = tid & 63;
  int h = tid >> 5, d = tid & 31;

  for (int t = tid; t < deg; t += 256) {
    int e = csr[base + t];
    s_eid[t] = e;
    s_tgt[t] = tgt[e];
  }
  __syncthreads();

  // Q_i: lane l holds dims 4l..4l+3
  float4 q4 = *(const float4*)&QKVI[(size_t)i * 1024 + 4 * l];

  // self score (wave 0): K from bf16 table
  if (w == 0) {
    u16x4 kb = *(const u16x4*)&Kb[(size_t)i * 256 + 4 * l];
    float4 k4 = make_float4(bf2f(kb.x), bf2f(kb.y), bf2f(kb.z), bf2f(kb.w));
    float c = dot4(q4, k4);
    c += __shfl_xor(c, 1); c += __shfl_xor(c, 2); c += __shfl_xor(c, 4);
    if ((l & 7) == 0) s_self[l >> 3] = c * scl;
  }

  // edge logits: 4 edges per wave iteration, batched loads
  for (int t0 = w; t0 < deg; t0 += 16) {
    float4 ef[4], k4[4];
#pragma unroll
    for (int u = 0; u < 4; ++u) {
      int t = t0 + 4 * u;
      if (t < deg) {
        ef[u] = *(const float4*)&Ef[(size_t)s_eid[t] * 256 + 4 * l];
        u16x4 kb = *(const u16x4*)&Kb[(size_t)s_tgt[t] * 256 + 4 * l];
        k4[u] = make_float4(bf2f(kb.x), bf2f(kb.y), bf2f(kb.z), bf2f(kb.w));
      }
    }
#pragma unroll
    for (int u = 0; u < 4; ++u) {
      int t = t0 + 4 * u;
      if (t < deg) {
        float c = dot4(q4, ef[u]) + dot4(ef[u], k4[u]) + dot4(q4, k4[u]);
        c += __shfl_xor(c, 1); c += __shfl_xor(c, 2); c += __shfl_xor(c, 4);
        if ((l & 7) == 0) s_sc[l >> 3][t] = c * scl;
      }
    }
  }

  // dedup (keep max eid per tgt), drop self-target
  for (int t = tid; t < deg; t += 256) {
    int tt = s_tgt[t], ee = s_eid[t];
    bool alive = (tt != i);
    if (alive)
      for (int u = 0; u < deg; ++u)
        if (s_tgt[u] == tt && s_eid[u] > ee) { alive = false; break; }
    s_alive[t] = alive ? 1 : 0;
  }
  __syncthreads();

  // softmax: 32 lanes per head; dead edges get weight exactly 0
  {
    float m = s_self[h];
    for (int t = d; t < deg; t += 32)
      if (s_alive[t]) m = fmaxf(m, s_sc[h][t]);
#pragma unroll
    for (int off = 16; off > 0; off >>= 1) m = fmaxf(m, __shfl_xor(m, off, 32));
    float lsum = 0.f;
    for (int t = d; t < deg; t += 32) {
      float wv = s_alive[t] ? expf(s_sc[h][t] - m) : 0.f;
      s_sc[h][t] = wv;
      lsum += wv;
    }
#pragma unroll
    for (int off = 16; off > 0; off >>= 1) lsum += __shfl_xor(lsum, off, 32);
    float wself = expf(s_self[h] - m);
    float inv = 1.f / (lsum + wself);
    if (d == 0) s_wself[h] = wself * inv;
    for (int t = d; t < deg; t += 32) s_sc[h][t] *= inv;
  }
  __syncthreads();

  // aggregate V from bf16 table (L2-resident); col = tid -> coalesced
  int col = tid;
  float accv = s_wself[h] * bf2f(Vb[(size_t)i * 256 + col]);
  int t0 = 0;
  for (; t0 + 4 <= deg; t0 += 4) {
    float vl[4];
#pragma unroll
    for (int u = 0; u < 4; ++u)
      vl[u] = bf2f(Vb[(size_t)s_tgt[t0 + u] * 256 + col]);
#pragma unroll
    for (int u = 0; u < 4; ++u)
      accv += s_sc[h][t0 + u] * vl[u];
  }
  for (; t0 < deg; ++t0)
    accv += s_sc[h][t0] * bf2f(Vb[(size_t)s_tgt[t0] * 256 + col]);
  agg[(size_t)i * 256 + col] = accv;
}

// ---------------------------------------------------------------------------
extern "C" void kernel_launch(void* const* d_in, const int* in_sizes, int n_in,
                              void* d_out, int out_size, void* d_ws, size_t ws_size,
                              hipStream_t stream) {
  (void)in_sizes; (void)n_in; (void)out_size; (void)ws_size;
  const float* x  = (const float*)d_in[0];
  const int*   ei = (const int*)d_in[1];
  const float* ea = (const float*)d_in[2];
  const float* Wq = (const float*)d_in[3];  const float* bq = (const float*)d_in[4];
  const float* Wk = (const float*)d_in[5];  const float* bk = (const float*)d_in[6];
  const float* Wv = (const float*)d_in[7];  const float* bv = (const float*)d_in[8];
  const float* We = (const float*)d_in[9];  const float* be = (const float*)d_in[10];
  const float* Wo = (const float*)d_in[11]; const float* bo = (const float*)d_in[12];
  const float* Wi = (const float*)d_in[13]; const float* bi = (const float*)d_in[14];
  const float* lng = (const float*)d_in[15]; const float* lnb = (const float*)d_in[16];

  const int* src = ei;
  const int* tgt = ei + N_EDGES;

  char* ws = (char*)d_ws;
  u16*   WcatT   = (u16*)(ws + 0);              //  512 KB
  u16*   WeT     = (u16*)(ws + 524288);         //  128 KB
  u16*   WoT     = (u16*)(ws + 655360);         //  128 KB
  float* bcat    = (float*)(ws + 786432);       //    4 KB
  float* QKVI    = (float*)(ws + 790528);       //   16 MB
  int*   deg     = (int*)(ws + 17567744);       //   16 KB
  int*   rowstart= (int*)(ws + 17584128);       //   16.25 KB
  int*   cursor  = (int*)(ws + 17600768);       //   16 KB
  int*   csr     = (int*)(ws + 17617152);       //  512 KB
  float* agg     = (float*)(ws + 18141440);     //    4 MB
  u16*   Kb      = (u16*)(ws + 22335744);       //    2 MB
  u16*   Vb      = (u16*)(ws + 24432896);       //    2 MB

  float* outN = (float*)d_out;
  float* outE = (float*)d_out + (size_t)N_NODES * DIM;

  prep_w_k<<<1552, 256, 0, stream>>>(Wq, Wk, Wv, Wi, We, Wo, bq, bk, bv, bi,
                                     WcatT, WeT, WoT, bcat, deg);

  hist_k<<<N_EDGES / 256, 256, 0, stream>>>(src, deg);
  scan_k<<<1, 1024, 0, stream>>>(deg, rowstart, cursor);
  scatter_k<<<N_EDGES / 256, 256, 0, stream>>>(src, cursor, csr);

  // merged: edge_out = ea @ We + be  AND  QKVI = x @ [Wq|Wk|Wv|Wi] + bcat
  gemm_all_k<<<1152, 512, 0, stream>>>(ea, WeT, be, outE, x, WcatT, bcat,
                                       QKVI, Kb, Vb);

  // fused logits + softmax + V aggregation
  node_attn_k<<<N_NODES, 256, 0, stream>>>(QKVI, outE, Kb, Vb,
                                           rowstart, csr, tgt, agg);

  // Wo GEMM + fused LayerNorm -> outN
  gemm_wo_k<<<N_NODES / 128, 512, 0, stream>>>(agg, WoT, bo, QKVI, lng, lnb, outN);
}

// Round 19
// 161.058 us; speedup vs baseline: 1.1714x; 1.0762x over previous
//
#include <hip/hip_runtime.h>

#define N_NODES 4096
#define N_EDGES 131072
#define DIM     256
#define HEADS   8
#define HDIM    32
#define MAXDEG  320
#define MAXDEGP 321   // (321h+t)%32 = (h+t)%32 -> 8 heads hit distinct banks

typedef unsigned short u16;
typedef unsigned int   u32;

using f32x4  = __attribute__((ext_vector_type(4))) float;
using bf16x8 = __attribute__((ext_vector_type(8))) short;
using u16x4  = __attribute__((ext_vector_type(4))) unsigned short;
using u16x8  = __attribute__((ext_vector_type(8))) unsigned short;

__device__ __forceinline__ u16 f2bf(float f) {
  u32 u = __float_as_uint(f);
  u += 0x7fffu + ((u >> 16) & 1u);   // RNE
  return (u16)(u >> 16);
}
__device__ __forceinline__ float bf2f(u16 u) {
  return __uint_as_float(((u32)u) << 16);
}
__device__ __forceinline__ float dot4(float4 a, float4 b) {
  return a.x * b.x + a.y * b.y + a.z * b.z + a.w * b.w;
}

// ---------------------------------------------------------------------------
// Weight prep v2: coalesced 64x64 LDS tile-transpose (blocks 0..95 = 6
// matrices x 16 tiles), bcat (block 96), cursor zeroing (blocks 97..100).
// ---------------------------------------------------------------------------
__global__ __launch_bounds__(256) void prep2_k(
    const float* __restrict__ Wq, const float* __restrict__ Wk,
    const float* __restrict__ Wv, const float* __restrict__ Wi,
    const float* __restrict__ We, const float* __restrict__ Wo,
    const float* __restrict__ bq, const float* __restrict__ bk,
    const float* __restrict__ bv, const float* __restrict__ bi,
    u16* __restrict__ WcatT, u16* __restrict__ WeT, u16* __restrict__ WoT,
    float* __restrict__ bcat, int* __restrict__ cursor)
{
  __shared__ float t[64][65];
  int b = blockIdx.x;
  int tid = threadIdx.x;
  if (b < 96) {
    int mat = b >> 4, tile = b & 15;
    int k0 = (tile >> 2) * 64, n0 = (tile & 3) * 64;
    const float* W = (mat == 0) ? Wq : (mat == 1) ? Wk : (mat == 2) ? Wv
                   : (mat == 3) ? Wi : (mat == 4) ? We : Wo;
    u16* dst; int nbase;
    if (mat < 4)      { dst = WcatT; nbase = mat * 256; }
    else if (mat == 4){ dst = WeT;   nbase = 0; }
    else              { dst = WoT;   nbase = 0; }
    int c = tid & 63, r0 = tid >> 6;
#pragma unroll
    for (int r = 0; r < 16; ++r) {
      int row = r0 + r * 4;
      t[row][c] = W[(size_t)(k0 + row) * 256 + n0 + c];   // coalesced read
    }
    __syncthreads();
#pragma unroll
    for (int r = 0; r < 16; ++r) {
      int nn = r0 + r * 4;            // n-index within tile
      // dst[(nbase+n0+nn)*256 + k0 + c] = W[k0+c][n0+nn]
      dst[(size_t)(nbase + n0 + nn) * 256 + k0 + c] = f2bf(t[c][nn]);
    }
  } else if (b == 96) {
#pragma unroll
    for (int j = 0; j < 4; ++j) {
      const float* bb = (j == 0) ? bq : (j == 1) ? bk : (j == 2) ? bv : bi;
      bcat[j * 256 + tid] = bb[tid];
    }
  } else {
    ((int4*)cursor)[(b - 97) * 256 + tid] = make_int4(0, 0, 0, 0);
  }
}

// ---------------------------------------------------------------------------
// 128x256 GEMM body, 512 threads / 8 waves. MODE 0: edge GEMM -> outE fp32.
// MODE 1: QKVI GEMM (+ compact bf16 Kb/Vb when the column tile covers K/V).
// MODE 2: Wo GEMM with fused LayerNorm(x_proj + preo) -> outN.
// nt A-loads (A read exactly once); LDS dbuf; lgkmcnt-only barrier; swizzle.
// ---------------------------------------------------------------------------
template<int MODE>
__device__ __forceinline__ void gemm_big_body(
    const float* __restrict__ A, const u16* __restrict__ BT,
    const float* __restrict__ bias, float* __restrict__ C, int Nn,
    int m0, int nc0,
    u16* __restrict__ Kb, u16* __restrict__ Vb,
    const float* __restrict__ QKVI, const float* __restrict__ lng,
    const float* __restrict__ lnb, float* __restrict__ outN,
    u16 (&As)[2][128 * 32], u16 (&Bs)[2][256 * 32])
{
  const int tid = threadIdx.x;          // 0..511
  const int w = tid >> 6, l = tid & 63;
  const int wr = w >> 2, wc = w & 3;
  const int fr = l & 15, hi = l >> 4;

  f32x4 pa[2];
  u16x8 pb[2];
  f32x4 acc[4][4] = {};

  auto loadstep = [&](int kt) {
#pragma unroll
    for (int i = 0; i < 2; ++i) {
      int j = tid + 512 * i;
      pa[i] = __builtin_nontemporal_load(
          (const f32x4*)(A + (size_t)(m0 + (j >> 3)) * 256 + kt * 32 + ((j & 7) << 2)));
    }
#pragma unroll
    for (int i = 0; i < 2; ++i) {
      int j = tid + 512 * i;
      pb[i] = *(const u16x8*)(BT + (size_t)(nc0 + (j >> 2)) * 256 + kt * 32 + ((j & 3) << 3));
    }
  };
  auto storestep = [&](int buf) {
#pragma unroll
    for (int i = 0; i < 2; ++i) {
      int j = tid + 512 * i;
      int row = j >> 3;
      int c16 = (j & 7) >> 1, half = j & 1;
      int swc = (c16 + ((row >> 1) & 3)) & 3;
      u16x4 u;
      u.x = f2bf(pa[i][0]); u.y = f2bf(pa[i][1]); u.z = f2bf(pa[i][2]); u.w = f2bf(pa[i][3]);
      *(u16x4*)&As[buf][row * 32 + swc * 8 + half * 4] = u;
    }
#pragma unroll
    for (int i = 0; i < 2; ++i) {
      int j = tid + 512 * i;
      int row = j >> 2;
      int swc = ((j & 3) + ((row >> 1) & 3)) & 3;
      *(u16x8*)&Bs[buf][row * 32 + swc * 8] = pb[i];
    }
  };

  loadstep(0);
  storestep(0);

#pragma unroll
  for (int kt = 0; kt < 8; ++kt) {
    if (kt < 7) loadstep(kt + 1);
    __builtin_amdgcn_sched_barrier(0);
    asm volatile("s_waitcnt lgkmcnt(0)" ::: "memory");
    __builtin_amdgcn_s_barrier();
    __builtin_amdgcn_sched_barrier(0);
    const int cur = kt & 1;
    bf16x8 a[4], b[4];
#pragma unroll
    for (int mi = 0; mi < 4; ++mi) {
      int rA = wr * 64 + mi * 16 + fr;
      int swc = (hi + ((rA >> 1) & 3)) & 3;
      a[mi] = *(const bf16x8*)&As[cur][rA * 32 + swc * 8];
    }
#pragma unroll
    for (int ni = 0; ni < 4; ++ni) {
      int rB = wc * 64 + ni * 16 + fr;
      int swc = (hi + ((rB >> 1) & 3)) & 3;
      b[ni] = *(const bf16x8*)&Bs[cur][rB * 32 + swc * 8];
    }
#pragma unroll
    for (int mi = 0; mi < 4; ++mi)
#pragma unroll
      for (int ni = 0; ni < 4; ++ni)
        acc[mi][ni] = __builtin_amdgcn_mfma_f32_16x16x32_bf16(
            b[ni], a[mi], acc[mi][ni], 0, 0, 0);
    if (kt < 7) storestep((kt + 1) & 1);
  }

  if constexpr (MODE == 0) {
#pragma unroll
    for (int mi = 0; mi < 4; ++mi) {
      int row = m0 + wr * 64 + mi * 16 + fr;
#pragma unroll
      for (int ni = 0; ni < 4; ++ni) {
        int col = wc * 64 + ni * 16 + hi * 4;
        float4 bv = *(const float4*)&bias[col];
        f32x4 v = acc[mi][ni];
        float4 o;
        o.x = v[0] + bv.x; o.y = v[1] + bv.y; o.z = v[2] + bv.z; o.w = v[3] + bv.w;
        *(float4*)&C[(size_t)row * 256 + col] = o;
      }
    }
  } else if constexpr (MODE == 1) {
#pragma unroll
    for (int mi = 0; mi < 4; ++mi) {
      int row = m0 + wr * 64 + mi * 16 + fr;
#pragma unroll
      for (int ni = 0; ni < 4; ++ni) {
        int col = nc0 + wc * 64 + ni * 16 + hi * 4;
        float4 bv = *(const float4*)&bias[col];
        f32x4 v = acc[mi][ni];
        float4 o;
        o.x = v[0] + bv.x; o.y = v[1] + bv.y; o.z = v[2] + bv.z; o.w = v[3] + bv.w;
        *(float4*)&C[(size_t)row * 1024 + col] = o;
        u16x4 ub;
        ub.x = f2bf(o.x); ub.y = f2bf(o.y); ub.z = f2bf(o.z); ub.w = f2bf(o.w);
        if (nc0 == 256) *(u16x4*)&Kb[(size_t)row * 256 + (col - 256)] = ub;
        if (nc0 == 512) *(u16x4*)&Vb[(size_t)row * 256 + (col - 512)] = ub;
      }
    }
  } else {
    // Wo GEMM + fused LayerNorm(x_proj + preo) -> outN
    __syncthreads();
    float* s_sum = (float*)&As[0][0];     // [128][16]
    float* s_sq  = (float*)&As[1][0];
#pragma unroll
    for (int mi = 0; mi < 4; ++mi) {
      int r = wr * 64 + mi * 16 + fr;
      int row = m0 + r;
      float ps = 0.f, pq = 0.f;
#pragma unroll
      for (int ni = 0; ni < 4; ++ni) {
        int col = wc * 64 + ni * 16 + hi * 4;
        float4 bv = *(const float4*)&bias[col];
        float4 xp = *(const float4*)&QKVI[(size_t)row * 1024 + 768 + col];
        acc[mi][ni][0] += bv.x + xp.x;
        acc[mi][ni][1] += bv.y + xp.y;
        acc[mi][ni][2] += bv.z + xp.z;
        acc[mi][ni][3] += bv.w + xp.w;
#pragma unroll
        for (int j = 0; j < 4; ++j) {
          float vv = acc[mi][ni][j];
          ps += vv; pq += vv * vv;
        }
      }
      s_sum[r * 16 + wc * 4 + hi] = ps;
      s_sq [r * 16 + wc * 4 + hi] = pq;
    }
    __syncthreads();
    float* s_mu = (float*)&Bs[0][0];
    float* s_rs = s_mu + 128;
    if (tid < 128) {
      float s = 0.f, q = 0.f;
#pragma unroll
      for (int k = 0; k < 16; ++k) { s += s_sum[tid * 16 + k]; q += s_sq[tid * 16 + k]; }
      float mu = s * (1.0f / 256.0f);
      float var = q * (1.0f / 256.0f) - mu * mu;
      s_mu[tid] = mu;
      s_rs[tid] = rsqrtf(var + 1e-5f);
    }
    __syncthreads();
#pragma unroll
    for (int mi = 0; mi < 4; ++mi) {
      int r = wr * 64 + mi * 16 + fr;
      int row = m0 + r;
      float mu = s_mu[r], rs = s_rs[r];
#pragma unroll
      for (int ni = 0; ni < 4; ++ni) {
        int col = wc * 64 + ni * 16 + hi * 4;
        float4 g4 = *(const float4*)&lng[col];
        float4 b4 = *(const float4*)&lnb[col];
        float4 o;
        o.x = (acc[mi][ni][0] - mu) * rs * g4.x + b4.x;
        o.y = (acc[mi][ni][1] - mu) * rs * g4.y + b4.y;
        o.z = (acc[mi][ni][2] - mu) * rs * g4.z + b4.z;
        o.w = (acc[mi][ni][3] - mu) * rs * g4.w + b4.w;
        *(float4*)&outN[(size_t)row * 256 + col] = o;
      }
    }
  }
}

// Merged dispatch: 1152 blocks = 1024 edge (128x256) + 128 QKVI, every 9th = QKVI.
__global__ __launch_bounds__(512) void gemm_all_k(
    const float* __restrict__ ea, const u16* __restrict__ WeT,
    const float* __restrict__ be, float* __restrict__ outE,
    const float* __restrict__ x, const u16* __restrict__ WcatT,
    const float* __restrict__ bcat, float* __restrict__ QKVI,
    u16* __restrict__ Kb, u16* __restrict__ Vb)
{
  __shared__ u16 As[2][128 * 32];
  __shared__ u16 Bs[2][256 * 32];
  int bid = blockIdx.x;
  int r = bid % 9, q = bid / 9;
  if (r < 8) {
    int j = q * 8 + r;
    gemm_big_body<0>(ea, WeT, be, outE, 256, j * 128, 0,
                     nullptr, nullptr, nullptr, nullptr, nullptr, nullptr, As, Bs);
  } else {
    gemm_big_body<1>(x, WcatT, bcat, QKVI, 1024, (q >> 2) * 128, (q & 3) * 256,
                     Kb, Vb, nullptr, nullptr, nullptr, nullptr, As, Bs);
  }
}

// Wo projection + fused LayerNorm: outN = LN(x_proj + agg @ Wo + bo)
__global__ __launch_bounds__(512) void gemm_wo_k(
    const float* __restrict__ agg, const u16* __restrict__ WoT,
    const float* __restrict__ bo, const float* __restrict__ QKVI,
    const float* __restrict__ lng, const float* __restrict__ lnb,
    float* __restrict__ outN)
{
  __shared__ u16 As[2][128 * 32];
  __shared__ u16 Bs[2][256 * 32];
  gemm_big_body<2>(agg, WoT, bo, nullptr, 256, blockIdx.x * 128, 0,
                   nullptr, nullptr, QKVI, lng, lnb, outN, As, Bs);
}

// ---------------------------------------------------------------------------
// Bucketed CSR in ONE kernel: p = atomicAdd(cursor[src]); slots[src*320+p]=e.
// cursor doubles as deg. (hist_k + scan_k deleted.)
// ---------------------------------------------------------------------------
__global__ __launch_bounds__(256) void scatter_k(const int* __restrict__ src,
                                                 int* __restrict__ cursor,
                                                 int* __restrict__ slots)
{
  int e = blockIdx.x * 256 + threadIdx.x;
  if (e < N_EDGES) {
    int s = src[e];
    int p = atomicAdd(&cursor[s], 1);
    if (p < MAXDEG) slots[(size_t)s * MAXDEG + p] = e;
  }
}

// ---------------------------------------------------------------------------
// Fused per-node kernel (coalesced layout + 4-deep MLP). Ef gathers fp32;
// K/V gathers hit compact bf16 tables (2MB each, L2-resident).
// ---------------------------------------------------------------------------
__global__ __launch_bounds__(256) void node_attn_k(
    const float* __restrict__ QKVI, const float* __restrict__ Ef,
    const u16* __restrict__ Kb, const u16* __restrict__ Vb,
    const int* __restrict__ cursor, const int* __restrict__ slots,
    const int* __restrict__ tgt, float* __restrict__ agg)
{
  __shared__ int   s_eid[MAXDEG];
  __shared__ int   s_tgt[MAXDEG];
  __shared__ float s_sc[HEADS][MAXDEGP];
  __shared__ unsigned char s_alive[MAXDEG];
  __shared__ float s_self[8];
  __shared__ float s_wself[8];

  const float scl = 0.17677669529663687f;
  int i = blockIdx.x;
  int deg = cursor[i];
  if (deg > MAXDEG) deg = MAXDEG;
  int tid = threadIdx.x;
  int w = tid >> 6, l = tid & 63;
  int h = tid >> 5, d = tid & 31;

  for (int t = tid; t < deg; t += 256) {
    int e = slots[(size_t)i * MAXDEG + t];
    s_eid[t] = e;
    s_tgt[t] = tgt[e];
  }
  __syncthreads();

  float4 q4 = *(const float4*)&QKVI[(size_t)i * 1024 + 4 * l];

  if (w == 0) {
    u16x4 kb = *(const u16x4*)&Kb[(size_t)i * 256 + 4 * l];
    float4 k4 = make_float4(bf2f(kb.x), bf2f(kb.y), bf2f(kb.z), bf2f(kb.w));
    float c = dot4(q4, k4);
    c += __shfl_xor(c, 1); c += __shfl_xor(c, 2); c += __shfl_xor(c, 4);
    if ((l & 7) == 0) s_self[l >> 3] = c * scl;
  }

  for (int t0 = w; t0 < deg; t0 += 16) {
    float4 ef[4], k4[4];
#pragma unroll
    for (int u = 0; u < 4; ++u) {
      int t = t0 + 4 * u;
      if (t < deg) {
        ef[u] = *(const float4*)&Ef[(size_t)s_eid[t] * 256 + 4 * l];
        u16x4 kb = *(const u16x4*)&Kb[(size_t)s_tgt[t] * 256 + 4 * l];
        k4[u] = make_float4(bf2f(kb.x), bf2f(kb.y), bf2f(kb.z), bf2f(kb.w));
      }
    }
#pragma unroll
    for (int u = 0; u < 4; ++u) {
      int t = t0 + 4 * u;
      if (t < deg) {
        float c = dot4(q4, ef[u]) + dot4(ef[u], k4[u]) + dot4(q4, k4[u]);
        c += __shfl_xor(c, 1); c += __shfl_xor(c, 2); c += __shfl_xor(c, 4);
        if ((l & 7) == 0) s_sc[l >> 3][t] = c * scl;
      }
    }
  }

  for (int t = tid; t < deg; t += 256) {
    int tt = s_tgt[t], ee = s_eid[t];
    bool alive = (tt != i);
    if (alive)
      for (int u = 0; u < deg; ++u)
        if (s_tgt[u] == tt && s_eid[u] > ee) { alive = false; break; }
    s_alive[t] = alive ? 1 : 0;
  }
  __syncthreads();

  {
    float m = s_self[h];
    for (int t = d; t < deg; t += 32)
      if (s_alive[t]) m = fmaxf(m, s_sc[h][t]);
#pragma unroll
    for (int off = 16; off > 0; off >>= 1) m = fmaxf(m, __shfl_xor(m, off, 32));
    float lsum = 0.f;
    for (int t = d; t < deg; t += 32) {
      float wv = s_alive[t] ? expf(s_sc[h][t] - m) : 0.f;
      s_sc[h][t] = wv;
      lsum += wv;
    }
#pragma unroll
    for (int off = 16; off > 0; off >>= 1) lsum += __shfl_xor(lsum, off, 32);
    float wself = expf(s_self[h] - m);
    float inv = 1.f / (lsum + wself);
    if (d == 0) s_wself[h] = wself * inv;
    for (int t = d; t < deg; t += 32) s_sc[h][t] *= inv;
  }
  __syncthreads();

  int col = tid;
  float accv = s_wself[h] * bf2f(Vb[(size_t)i * 256 + col]);
  int t0 = 0;
  for (; t0 + 4 <= deg; t0 += 4) {
    float vl[4];
#pragma unroll
    for (int u = 0; u < 4; ++u)
      vl[u] = bf2f(Vb[(size_t)s_tgt[t0 + u] * 256 + col]);
#pragma unroll
    for (int u = 0; u < 4; ++u)
      accv += s_sc[h][t0 + u] * vl[u];
  }
  for (; t0 < deg; ++t0)
    accv += s_sc[h][t0] * bf2f(Vb[(size_t)s_tgt[t0] * 256 + col]);
  agg[(size_t)i * 256 + col] = accv;
}

// ---------------------------------------------------------------------------
extern "C" void kernel_launch(void* const* d_in, const int* in_sizes, int n_in,
                              void* d_out, int out_size, void* d_ws, size_t ws_size,
                              hipStream_t stream) {
  (void)in_sizes; (void)n_in; (void)out_size; (void)ws_size;
  const float* x  = (const float*)d_in[0];
  const int*   ei = (const int*)d_in[1];
  const float* ea = (const float*)d_in[2];
  const float* Wq = (const float*)d_in[3];  const float* bq = (const float*)d_in[4];
  const float* Wk = (const float*)d_in[5];  const float* bk = (const float*)d_in[6];
  const float* Wv = (const float*)d_in[7];  const float* bv = (const float*)d_in[8];
  const float* We = (const float*)d_in[9];  const float* be = (const float*)d_in[10];
  const float* Wo = (const float*)d_in[11]; const float* bo = (const float*)d_in[12];
  const float* Wi = (const float*)d_in[13]; const float* bi = (const float*)d_in[14];
  const float* lng = (const float*)d_in[15]; const float* lnb = (const float*)d_in[16];

  const int* src = ei;
  const int* tgt = ei + N_EDGES;

  char* ws = (char*)d_ws;
  u16*   WcatT   = (u16*)(ws + 0);              //  512 KB
  u16*   WeT     = (u16*)(ws + 524288);         //  128 KB
  u16*   WoT     = (u16*)(ws + 655360);         //  128 KB
  float* bcat    = (float*)(ws + 786432);       //    4 KB
  float* QKVI    = (float*)(ws + 790528);       //   16 MB
  int*   cursor  = (int*)(ws + 17567744);       //   16 KB
  int*   slots   = (int*)(ws + 17584128);       // 5.24 MB (4096 x 320)
  float* agg     = (float*)(ws + 22827008);     //    4 MB
  u16*   Kb      = (u16*)(ws + 27021312);       //    2 MB
  u16*   Vb      = (u16*)(ws + 29118464);       //    2 MB

  float* outN = (float*)d_out;
  float* outE = (float*)d_out + (size_t)N_NODES * DIM;

  // weight transpose (coalesced) + bcat + cursor zeroing
  prep2_k<<<101, 256, 0, stream>>>(Wq, Wk, Wv, Wi, We, Wo, bq, bk, bv, bi,
                                   WcatT, WeT, WoT, bcat, cursor);

  // bucketed CSR (one kernel)
  scatter_k<<<N_EDGES / 256, 256, 0, stream>>>(src, cursor, slots);

  // merged: edge_out = ea @ We + be  AND  QKVI = x @ [Wq|Wk|Wv|Wi] + bcat
  gemm_all_k<<<1152, 512, 0, stream>>>(ea, WeT, be, outE, x, WcatT, bcat,
                                       QKVI, Kb, Vb);

  // fused logits + softmax + V aggregation
  node_attn_k<<<N_NODES, 256, 0, stream>>>(QKVI, outE, Kb, Vb,
                                           cursor, slots, tgt, agg);

  // Wo GEMM + fused LayerNorm -> outN
  gemm_wo_k<<<N_NODES / 128, 512, 0, stream>>>(agg, WoT, bo, QKVI, lng, lnb, outN);
}